// Round 1
// baseline (103.397 us; speedup 1.0000x reference)
//
#include <hip/hip_runtime.h>
#include <hip/hip_bf16.h>

// SplineLoss: the reference evaluates a not-a-knot cubic spline at INTEGER
// sample times t = 0,10,...,8190 with knots at integers 0..8191. Since
// idx == sample_times and the local parameter t-idx == 0 for every sample,
// _eval_spline reduces EXACTLY to yT[sample_times] (the slope solve is
// multiplied by 0). The output is therefore exactly:
//   mean_{b<1024, j<820} (true[b,10j] - pred[b,10j])^2
//
// Memory: stride-10 floats = 40B < 64B line, so every line of both 32MB
// arrays must be fetched anyway -> read everything coalesced (float4) and
// predicate on t%10==0. Minimum HBM traffic = 67MB, roofline ~10.6us.

#define B_ROWS   1024
#define N_COLS   8192
#define STRIDE   10
#define N_SAMP   820          // ceil(8192/10) -> indices 0..8190
#define BLOCK    256

__global__ __launch_bounds__(BLOCK)
void spline_loss_kernel(const float* __restrict__ tf,
                        const float* __restrict__ pf,
                        float* __restrict__ out) {
    const int b = blockIdx.x;                     // one block per batch row
    const float4* t4 = (const float4*)(tf + (size_t)b * N_COLS);
    const float4* p4 = (const float4*)(pf + (size_t)b * N_COLS);

    float acc = 0.0f;
    // 8192/4 = 2048 float4 groups per row; 256 threads -> 8 iterations.
    for (int g = threadIdx.x; g < N_COLS / 4; g += BLOCK) {
        float4 a = t4[g];
        float4 c = p4[g];
        int t = g << 2;
        float d0 = a.x - c.x;
        float d1 = a.y - c.y;
        float d2 = a.z - c.z;
        float d3 = a.w - c.w;
        if ((t    ) % STRIDE == 0) acc += d0 * d0;
        if ((t + 1) % STRIDE == 0) acc += d1 * d1;
        if ((t + 2) % STRIDE == 0) acc += d2 * d2;
        if ((t + 3) % STRIDE == 0) acc += d3 * d3;
    }

    // wave-64 shuffle reduction
    #pragma unroll
    for (int off = 32; off > 0; off >>= 1)
        acc += __shfl_down(acc, off, 64);

    __shared__ float wsum[BLOCK / 64];
    const int lane = threadIdx.x & 63;
    const int wid  = threadIdx.x >> 6;
    if (lane == 0) wsum[wid] = acc;
    __syncthreads();

    if (threadIdx.x == 0) {
        float s = 0.0f;
        #pragma unroll
        for (int w = 0; w < BLOCK / 64; ++w) s += wsum[w];
        const float inv = 1.0f / (float)(B_ROWS * N_SAMP);
        atomicAdd(out, s * inv);   // device-scope by default on CDNA
    }
}

extern "C" void kernel_launch(void* const* d_in, const int* in_sizes, int n_in,
                              void* d_out, int out_size, void* d_ws, size_t ws_size,
                              hipStream_t stream) {
    const float* tf = (const float*)d_in[0];   // true_frames  (1024, 8192) f32
    const float* pf = (const float*)d_in[1];   // predicted_frames
    float* out = (float*)d_out;                // scalar f32

    // d_out is re-poisoned to 0xAA before every timed launch: zero it
    // (stream-ordered memset is graph-capture safe; the harness uses it too).
    hipMemsetAsync(out, 0, sizeof(float), stream);

    spline_loss_kernel<<<B_ROWS, BLOCK, 0, stream>>>(tf, pf, out);
}

// Round 2
// 93.301 us; speedup vs baseline: 1.1082x; 1.1082x over previous
//
#include <hip/hip_runtime.h>
#include <hip/hip_bf16.h>

// SplineLoss: reference evaluates a not-a-knot cubic spline at INTEGER sample
// times t=0,10,...,8190 with knots at integers 0..8191 -> local parameter is
// exactly 0 for every sample, so the spline solve vanishes and the result is
// exactly:  mean_{b<1024, j<820} (true[b,10j] - pred[b,10j])^2
//
// Every 64B line of both 32MB inputs contains a multiple-of-10 element
// (stride 40B < 64B), so minimum HBM traffic = 64MB -> stream everything
// coalesced (float4) and predicate. Within a float4 group g (t=4g), the
// multiples of 10 land only at component .x when g%5==0 and .z when g%5==2
// (pattern period lcm(4,10)=20 elements = 5 groups; 2 samples per 20 -> 820/row).
//
// Two-stage reduction through d_ws (no atomics: 1024+ same-address atomicAdds
// serialize at one L2 bank; also lets stage 2 WRITE out[0], killing the
// d_out memset dispatch).

#define B_ROWS   1024
#define N_COLS   8192
#define N_SAMP   820
#define BLOCK    256
#define SPLIT    2                         // blocks per row
#define GRID     (B_ROWS * SPLIT)          // 2048 partials
#define GROUPS_PER_ROW   (N_COLS / 4)      // 2048 float4 groups
#define GROUPS_PER_BLOCK (GROUPS_PER_ROW / SPLIT)  // 1024

__global__ __launch_bounds__(BLOCK)
void spline_partial_kernel(const float* __restrict__ tf,
                           const float* __restrict__ pf,
                           float* __restrict__ partial) {
    const int b    = blockIdx.x >> 1;          // row
    const int half = blockIdx.x & 1;           // which half of the row
    const float4* t4 = (const float4*)(tf + (size_t)b * N_COLS);
    const float4* p4 = (const float4*)(pf + (size_t)b * N_COLS);

    float acc = 0.0f;
    #pragma unroll
    for (int k = 0; k < GROUPS_PER_BLOCK / BLOCK; ++k) {   // 4 iters
        const int g = half * GROUPS_PER_BLOCK + k * BLOCK + threadIdx.x;
        float4 a = t4[g];
        float4 c = p4[g];
        const int r = g % 5;                   // magic-mul, cheap (VALUBusy ~4%)
        const float d0 = a.x - c.x;
        const float d2 = a.z - c.z;
        acc += (r == 0) ? d0 * d0 : 0.0f;
        acc += (r == 2) ? d2 * d2 : 0.0f;
    }

    #pragma unroll
    for (int off = 32; off > 0; off >>= 1)
        acc += __shfl_down(acc, off, 64);

    __shared__ float wsum[BLOCK / 64];
    const int lane = threadIdx.x & 63;
    const int wid  = threadIdx.x >> 6;
    if (lane == 0) wsum[wid] = acc;
    __syncthreads();

    if (threadIdx.x == 0) {
        float s = 0.0f;
        #pragma unroll
        for (int w = 0; w < BLOCK / 64; ++w) s += wsum[w];
        partial[blockIdx.x] = s;               // one plain store per block
    }
}

__global__ __launch_bounds__(BLOCK)
void spline_final_kernel(const float* __restrict__ partial,
                         float* __restrict__ out) {
    float acc = 0.0f;
    #pragma unroll
    for (int k = 0; k < GRID / BLOCK; ++k)     // 8 iters, coalesced
        acc += partial[k * BLOCK + threadIdx.x];

    #pragma unroll
    for (int off = 32; off > 0; off >>= 1)
        acc += __shfl_down(acc, off, 64);

    __shared__ float wsum[BLOCK / 64];
    const int lane = threadIdx.x & 63;
    const int wid  = threadIdx.x >> 6;
    if (lane == 0) wsum[wid] = acc;
    __syncthreads();

    if (threadIdx.x == 0) {
        float s = 0.0f;
        #pragma unroll
        for (int w = 0; w < BLOCK / 64; ++w) s += wsum[w];
        out[0] = s * (1.0f / (float)(B_ROWS * N_SAMP));  // overwrite: no memset needed
    }
}

extern "C" void kernel_launch(void* const* d_in, const int* in_sizes, int n_in,
                              void* d_out, int out_size, void* d_ws, size_t ws_size,
                              hipStream_t stream) {
    const float* tf = (const float*)d_in[0];   // true_frames  (1024, 8192) f32
    const float* pf = (const float*)d_in[1];   // predicted_frames
    float* out     = (float*)d_out;            // scalar f32
    float* partial = (float*)d_ws;             // 2048 floats = 8 KB of scratch

    spline_partial_kernel<<<GRID, BLOCK, 0, stream>>>(tf, pf, partial);
    spline_final_kernel<<<1, BLOCK, 0, stream>>>(partial, out);
}